// Round 5
// baseline (800.240 us; speedup 1.0000x reference)
//
#include <hip/hip_runtime.h>
#include <math.h>

// Problem constants (fixed by the reference: N=16384, H=16, C=32, NE=196608)
#define H_DIM 16
#define C_DIM 32
#define HC_DIM (H_DIM * C_DIM)   // 512
#define EPSF 1e-5f
#define QK_SCALE 0.17677669529663687f   // 1/sqrt(32)

__device__ __forceinline__ float reduce8(float x) {
    // sum across the 8 lanes that share one head (xor 1/2/4 stays in-wave)
    x += __shfl_xor(x, 1);
    x += __shfl_xor(x, 2);
    x += __shfl_xor(x, 4);
    return x;
}
__device__ __forceinline__ float reduce8_max(float x) {
    x = fmaxf(x, __shfl_xor(x, 1));
    x = fmaxf(x, __shfl_xor(x, 2));
    x = fmaxf(x, __shfl_xor(x, 4));
    return x;
}

// Nontemporal float4 load via clang ext_vector (float4 itself is a struct).
typedef float f4_raw __attribute__((ext_vector_type(4)));
__device__ __forceinline__ float4 nt_load4(const float* p) {
    f4_raw r = __builtin_nontemporal_load((const f4_raw*)p);
    return make_float4(r.x, r.y, r.z, r.w);
}
__device__ __forceinline__ void nt_store4(float* p, float4 v) {
    f4_raw r = {v.x, v.y, v.z, v.w};
    __builtin_nontemporal_store(r, (f4_raw*)p);
}

__global__ void zero_kernel(int* __restrict__ p, int n) {
    int i = blockIdx.x * blockDim.x + threadIdx.x;
    if (i < n) p[i] = 0;
}

// Fused pre-pass, disjoint block ranges:
//   [0, histBlocks)            : dst histogram (4 edges/thread via int4)
//   [histBlocks, +qkBlocks)    : qns[row] = rms(q)*wq*qk_scale   (8 lanes/row)
//   [histBlocks+qkBlocks, ...) : knw[row] = rms(k)*wk            (8 lanes/row)
__global__ __launch_bounds__(256)
void prep_kernel(const int* __restrict__ edst, int* __restrict__ counts,
                 const float* __restrict__ q, const float* __restrict__ k,
                 const float* __restrict__ wq, const float* __restrict__ wk,
                 float* __restrict__ qns, float* __restrict__ knw,
                 int ne, int rows, int histBlocks, int qkBlocks) {
    int b = blockIdx.x;
    if (b < histBlocks) {
        int i4 = (b * 256 + threadIdx.x) * 4;
        if (i4 + 4 <= ne) {
            int4 d = *(const int4*)(edst + i4);
            atomicAdd(&counts[d.x], 1);
            atomicAdd(&counts[d.y], 1);
            atomicAdd(&counts[d.z], 1);
            atomicAdd(&counts[d.w], 1);
        } else {
            for (int j = i4; j < ne; ++j) atomicAdd(&counts[edst[j]], 1);
        }
        return;
    }
    b -= histBlocks;
    const bool isQ = (b < qkBlocks);
    if (!isQ) b -= qkBlocks;
    int gt = b * 256 + threadIdx.x;
    int row = gt >> 3;
    if (row >= rows) return;
    const int c4 = (gt & 7) << 2;
    const size_t off = (size_t)row * C_DIM + c4;
    const float* src = isQ ? q : k;
    float4 x = *(const float4*)(src + off);
    float ss = x.x * x.x + x.y * x.y + x.z * x.z + x.w * x.w;
    ss = reduce8(ss);
    float inv = rsqrtf(ss * (1.0f / C_DIM) + EPSF);
    if (isQ) {
        float4 w = *(const float4*)(wq + c4);
        *(float4*)(qns + off) = make_float4(x.x * inv * w.x * QK_SCALE,
                                            x.y * inv * w.y * QK_SCALE,
                                            x.z * inv * w.z * QK_SCALE,
                                            x.w * inv * w.w * QK_SCALE);
    } else {
        float4 w = *(const float4*)(wk + c4);
        *(float4*)(knw + off) = make_float4(x.x * inv * w.x, x.y * inv * w.y,
                                            x.z * inv * w.z, x.w * inv * w.w);
    }
}

// Single-block exclusive scan over counts[n] -> offsets[n+1].
// 16 ints/thread (int4 x4): 2 barriers per 16384-chunk.
__global__ __launch_bounds__(1024)
void scan_kernel(const int* __restrict__ counts, int* __restrict__ offsets, int n) {
    __shared__ int wsum[16];
    __shared__ int carry_s;
    const int tid = threadIdx.x;
    const int lane = tid & 63;
    const int wid = tid >> 6;
    if (tid == 0) carry_s = 0;
    __syncthreads();
    for (int b0 = 0; b0 < n; b0 += 16384) {
        const int base = b0 + tid * 16;
        int c[16];
        if (base + 16 <= n) {
            const int4* p = (const int4*)(counts + base);
            int4 t0 = p[0], t1 = p[1], t2 = p[2], t3 = p[3];
            c[0]=t0.x; c[1]=t0.y; c[2]=t0.z; c[3]=t0.w;
            c[4]=t1.x; c[5]=t1.y; c[6]=t1.z; c[7]=t1.w;
            c[8]=t2.x; c[9]=t2.y; c[10]=t2.z; c[11]=t2.w;
            c[12]=t3.x; c[13]=t3.y; c[14]=t3.z; c[15]=t3.w;
        } else {
            #pragma unroll
            for (int j = 0; j < 16; ++j) c[j] = (base + j < n) ? counts[base + j] : 0;
        }
        int s = 0;
        #pragma unroll
        for (int j = 0; j < 16; ++j) s += c[j];
        int v = s;
        #pragma unroll
        for (int off = 1; off < 64; off <<= 1) {
            int y = __shfl_up(v, off);
            if (lane >= off) v += y;
        }
        if (lane == 63) wsum[wid] = v;
        __syncthreads();
        if (wid == 0 && lane < 16) {
            int w = wsum[lane];
            #pragma unroll
            for (int off = 1; off < 16; off <<= 1) {
                int y = __shfl_up(w, off);
                if (lane >= off) w += y;
            }
            wsum[lane] = w;
        }
        __syncthreads();
        const int carry = carry_s;
        int p = carry + (wid ? wsum[wid - 1] : 0) + (v - s);  // exclusive prefix
        int o[16];
        #pragma unroll
        for (int j = 0; j < 16; ++j) { o[j] = p; p += c[j]; }
        if (base + 16 <= n) {
            int4* qo = (int4*)(offsets + base);
            qo[0] = make_int4(o[0], o[1], o[2], o[3]);
            qo[1] = make_int4(o[4], o[5], o[6], o[7]);
            qo[2] = make_int4(o[8], o[9], o[10], o[11]);
            qo[3] = make_int4(o[12], o[13], o[14], o[15]);
        } else {
            #pragma unroll
            for (int j = 0; j < 16; ++j)
                if (base + j < n) offsets[base + j] = o[j];
        }
        if (n - 1 >= base && n - 1 < base + 16) offsets[n] = p;  // grand total
        __syncthreads();
        if (tid == 0) carry_s = carry + wsum[15];
        __syncthreads();
    }
}

// 4 edges per thread via int4 loads of esrc/edst.
__global__ void scatter_kernel(const int* __restrict__ esrc, const int* __restrict__ edst,
                               const int* __restrict__ offsets, int* __restrict__ cursor,
                               int2* __restrict__ perm, int ne) {
    int i4 = (blockIdx.x * blockDim.x + threadIdx.x) * 4;
    if (i4 + 4 <= ne) {
        int4 d = *(const int4*)(edst + i4);
        int4 s = *(const int4*)(esrc + i4);
        int p0 = offsets[d.x] + atomicAdd(&cursor[d.x], 1);
        perm[p0] = make_int2(s.x, i4 + 0);
        int p1 = offsets[d.y] + atomicAdd(&cursor[d.y], 1);
        perm[p1] = make_int2(s.y, i4 + 1);
        int p2 = offsets[d.z] + atomicAdd(&cursor[d.z], 1);
        perm[p2] = make_int2(s.z, i4 + 2);
        int p3 = offsets[d.w] + atomicAdd(&cursor[d.w], 1);
        perm[p3] = make_int2(s.w, i4 + 3);
    } else {
        for (int j = i4; j < ne; ++j) {
            int d = edst[j];
            int pos = offsets[d] + atomicAdd(&cursor[d], 1);
            perm[pos] = make_int2(esrc[j], j);
        }
    }
}

// Phase S (edge order): sbuf[eid,h] = qns[dst]·(knw[src] + e[eid]).
// e streams SEQUENTIALLY (403 MB at full BW); gathers touch only qns/knw
// (67 MB reuse-hot working set). 2 edges per 256-thread block.
__global__ __launch_bounds__(256, 8)
void score_kernel(const float* __restrict__ qns, const float* __restrict__ knw,
                  const float* __restrict__ e,
                  const int* __restrict__ esrc, const int* __restrict__ edst,
                  float* __restrict__ sbuf, int ne) {
    const int t = threadIdx.x;
    const int eid = blockIdx.x * 2 + (t >> 7);
    if (eid >= ne) return;
    const int tt = t & 127;
    const int hc = tt << 2;
    const int h = tt >> 3;
    const int src = esrc[eid];
    const int dst = edst[eid];
    const float4 ev = nt_load4(e + (size_t)eid * HC_DIM + hc);
    const float4 kv = *(const float4*)(knw + (size_t)src * HC_DIM + hc);
    const float4 qv = *(const float4*)(qns + (size_t)dst * HC_DIM + hc);
    float d = qv.x * (kv.x + ev.x) + qv.y * (kv.y + ev.y)
            + qv.z * (kv.z + ev.z) + qv.w * (kv.w + ev.w);
    d = reduce8(d);
    if ((tt & 7) == 0) sbuf[(size_t)eid * H_DIM + h] = d;
}

// Phase V (dst order): per-node two-sweep softmax from precomputed scores,
// then accumulate alpha*(v+e). No per-edge online-rescale chain; the inner
// loop is pure load+fma with a 1-deep prefetch.
__global__ __launch_bounds__(128, 8)
void value_kernel(const float* __restrict__ v, const float* __restrict__ e,
                  const float* __restrict__ sbuf,
                  const int* __restrict__ offsets, const int2* __restrict__ perm,
                  float* __restrict__ out)
{
    const int node = blockIdx.x;
    const int t = threadIdx.x;
    const int hc = t << 2;
    const int h = t >> 3;
    const int lane8 = t & 7;
    const int node_off = node * HC_DIM + hc;

    const int row0 = offsets[node];
    const int row1 = offsets[node + 1];
    if (row0 >= row1) {   // empty node -> 0 (matches ref)
        nt_store4(out + node_off, make_float4(0.f, 0.f, 0.f, 0.f));
        return;
    }

    // Sweep 1 (lane-parallel over edges): per-lane online (m,l), then merge 8 lanes.
    float mr = -INFINITY, lr = 0.0f;
    for (int j = row0 + lane8; j < row1; j += 8) {
        float sv = sbuf[(size_t)perm[j].y * H_DIM + h];
        float mn = fmaxf(mr, sv);
        lr = lr * __expf(mr - mn) + __expf(sv - mn);
        mr = mn;
    }
    const float M = reduce8_max(mr);
    float lc = (lr > 0.0f) ? lr * __expf(mr - M) : 0.0f;
    const float l = reduce8(lc);
    const float invl = 1.0f / l;   // l >= 1 when node non-empty

    // Sweep 2: acc += exp(s - M) * (v + e), 1-deep prefetch.
    float4 acc = make_float4(0.f, 0.f, 0.f, 0.f);
    int2 p = perm[row0];
    float4 ev = nt_load4(e + (size_t)p.y * HC_DIM + hc);
    float4 vv = *(const float4*)(v + (size_t)p.x * HC_DIM + hc);
    float sv = sbuf[(size_t)p.y * H_DIM + h];
    for (int j = row0; j + 1 < row1; ++j) {
        int2 p1 = perm[j + 1];
        float4 ev1 = nt_load4(e + (size_t)p1.y * HC_DIM + hc);
        float4 vv1 = *(const float4*)(v + (size_t)p1.x * HC_DIM + hc);
        float sv1 = sbuf[(size_t)p1.y * H_DIM + h];
        float al = __expf(sv - M);
        acc.x += al * (vv.x + ev.x);
        acc.y += al * (vv.y + ev.y);
        acc.z += al * (vv.z + ev.z);
        acc.w += al * (vv.w + ev.w);
        ev = ev1; vv = vv1; sv = sv1;
    }
    float al = __expf(sv - M);
    acc.x += al * (vv.x + ev.x);
    acc.y += al * (vv.y + ev.y);
    acc.z += al * (vv.z + ev.z);
    acc.w += al * (vv.w + ev.w);

    nt_store4(out + node_off, make_float4(acc.x * invl, acc.y * invl,
                                          acc.z * invl, acc.w * invl));
}

extern "C" void kernel_launch(void* const* d_in, const int* in_sizes, int n_in,
                              void* d_out, int out_size, void* d_ws, size_t ws_size,
                              hipStream_t stream) {
    const float* q  = (const float*)d_in[0];
    const float* k  = (const float*)d_in[1];
    const float* v  = (const float*)d_in[2];
    const float* e  = (const float*)d_in[3];
    const float* wq = (const float*)d_in[4];
    const float* wk = (const float*)d_in[5];
    const int* esrc = (const int*)d_in[6];
    const int* edst = (const int*)d_in[7];
    float* out = (float*)d_out;

    const int NE = in_sizes[6];
    const int HC = in_sizes[3] / NE;      // H*C
    const int N  = in_sizes[0] / HC;      // 16384

    // workspace layout (16B-aligned chunks first):
    //   perm[NE] int2 | qns[N*HC] f32 | knw[N*HC] f32 | sbuf[NE*H] f32
    //   | counts[N] | cursor[N] | offsets[N+1]
    char* wsp = (char*)d_ws;
    int2*  perm = (int2*)wsp;                 wsp += (size_t)NE * sizeof(int2);
    float* qns  = (float*)wsp;                wsp += (size_t)N * HC_DIM * sizeof(float);
    float* knw  = (float*)wsp;                wsp += (size_t)N * HC_DIM * sizeof(float);
    float* sbuf = (float*)wsp;                wsp += (size_t)NE * H_DIM * sizeof(float);
    int* counts  = (int*)wsp;
    int* cursor  = counts + N;
    int* offsets = cursor + N;

    const int rows = N * H_DIM;
    const int histBlocks = (NE / 4 + 255) / 256;
    const int qkBlocks   = (rows * 8 + 255) / 256;

    zero_kernel<<<(2 * N + 255) / 256, 256, 0, stream>>>(counts, 2 * N);
    prep_kernel<<<histBlocks + 2 * qkBlocks, 256, 0, stream>>>(
        edst, counts, q, k, wq, wk, qns, knw, NE, rows, histBlocks, qkBlocks);
    scan_kernel<<<1, 1024, 0, stream>>>(counts, offsets, N);
    scatter_kernel<<<(NE / 4 + 255) / 256, 256, 0, stream>>>(esrc, edst, offsets, cursor,
                                                             perm, NE);
    score_kernel<<<(NE + 1) / 2, 256, 0, stream>>>(qns, knw, e, esrc, edst, sbuf, NE);
    value_kernel<<<N, 128, 0, stream>>>(v, e, sbuf, offsets, perm, out);
}

// Round 12
// 706.346 us; speedup vs baseline: 1.1329x; 1.1329x over previous
//
#include <hip/hip_runtime.h>
#include <math.h>

// Problem constants (fixed by the reference: N=16384, H=16, C=32, NE=196608)
#define H_DIM 16
#define C_DIM 32
#define HC_DIM (H_DIM * C_DIM)   // 512
#define EPSF 1e-5f
#define QK_SCALE 0.17677669529663687f   // 1/sqrt(32)
#define NBUCK 8                          // src-locality buckets (see scatter key)

__device__ __forceinline__ float reduce8(float x) {
    // sum across the 8 lanes that share one head (xor 1/2/4 stays in-wave)
    x += __shfl_xor(x, 1);
    x += __shfl_xor(x, 2);
    x += __shfl_xor(x, 4);
    return x;
}

// Nontemporal float4 load via clang ext_vector (float4 itself is a struct).
typedef float f4_raw __attribute__((ext_vector_type(4)));
__device__ __forceinline__ float4 nt_load4(const float* p) {
    f4_raw r = __builtin_nontemporal_load((const f4_raw*)p);
    return make_float4(r.x, r.y, r.z, r.w);
}
__device__ __forceinline__ void nt_store4(float* p, float4 v) {
    f4_raw r = {v.x, v.y, v.z, v.w};
    __builtin_nontemporal_store(r, (f4_raw*)p);
}

__global__ void zero_kernel(int* __restrict__ p, int n) {
    int i = blockIdx.x * blockDim.x + threadIdx.x;
    if (i < n) p[i] = 0;
}

// Fused pre-pass, disjoint block ranges:
//   [0, histBlocks)  : histogram of key = dst*NBUCK + (src>>bshift)
//   [histBlocks, ..) : knw[row] = rms(k[row])*wk  (8 lanes per (n,h) row)
__global__ __launch_bounds__(256)
void prep_kernel(const int* __restrict__ esrc, const int* __restrict__ edst,
                 int* __restrict__ counts,
                 const float* __restrict__ k, const float* __restrict__ wk,
                 float* __restrict__ knw,
                 int ne, int rows, int histBlocks, int bshift) {
    int b = blockIdx.x;
    if (b < histBlocks) {
        int i4 = (b * 256 + threadIdx.x) * 4;
        if (i4 + 4 <= ne) {
            int4 d = *(const int4*)(edst + i4);
            int4 s = *(const int4*)(esrc + i4);
            atomicAdd(&counts[d.x * NBUCK + (s.x >> bshift)], 1);
            atomicAdd(&counts[d.y * NBUCK + (s.y >> bshift)], 1);
            atomicAdd(&counts[d.z * NBUCK + (s.z >> bshift)], 1);
            atomicAdd(&counts[d.w * NBUCK + (s.w >> bshift)], 1);
        } else {
            for (int j = i4; j < ne; ++j)
                atomicAdd(&counts[edst[j] * NBUCK + (esrc[j] >> bshift)], 1);
        }
        return;
    }
    int gt = (b - histBlocks) * 256 + threadIdx.x;
    int row = gt >> 3;
    if (row >= rows) return;
    const int c4 = (gt & 7) << 2;
    const size_t off = (size_t)row * C_DIM + c4;
    float4 x = *(const float4*)(k + off);
    float ss = x.x * x.x + x.y * x.y + x.z * x.z + x.w * x.w;
    ss = reduce8(ss);
    float inv = rsqrtf(ss * (1.0f / C_DIM) + EPSF);
    float4 w = *(const float4*)(wk + c4);
    *(float4*)(knw + off) = make_float4(x.x * inv * w.x, x.y * inv * w.y,
                                        x.z * inv * w.z, x.w * inv * w.w);
}

// Single-block exclusive scan over counts[n] -> offsets[n+1].
// 16 ints/thread (int4 x4): 2 barriers per 16384-chunk; n may span chunks.
__global__ __launch_bounds__(1024)
void scan_kernel(const int* __restrict__ counts, int* __restrict__ offsets, int n) {
    __shared__ int wsum[16];
    __shared__ int carry_s;
    const int tid = threadIdx.x;
    const int lane = tid & 63;
    const int wid = tid >> 6;
    if (tid == 0) carry_s = 0;
    __syncthreads();
    for (int b0 = 0; b0 < n; b0 += 16384) {
        const int base = b0 + tid * 16;
        int c[16];
        if (base + 16 <= n) {
            const int4* p = (const int4*)(counts + base);
            int4 t0 = p[0], t1 = p[1], t2 = p[2], t3 = p[3];
            c[0]=t0.x; c[1]=t0.y; c[2]=t0.z; c[3]=t0.w;
            c[4]=t1.x; c[5]=t1.y; c[6]=t1.z; c[7]=t1.w;
            c[8]=t2.x; c[9]=t2.y; c[10]=t2.z; c[11]=t2.w;
            c[12]=t3.x; c[13]=t3.y; c[14]=t3.z; c[15]=t3.w;
        } else {
            #pragma unroll
            for (int j = 0; j < 16; ++j) c[j] = (base + j < n) ? counts[base + j] : 0;
        }
        int s = 0;
        #pragma unroll
        for (int j = 0; j < 16; ++j) s += c[j];
        int v = s;
        #pragma unroll
        for (int off = 1; off < 64; off <<= 1) {
            int y = __shfl_up(v, off);
            if (lane >= off) v += y;
        }
        if (lane == 63) wsum[wid] = v;
        __syncthreads();
        if (wid == 0 && lane < 16) {
            int w = wsum[lane];
            #pragma unroll
            for (int off = 1; off < 16; off <<= 1) {
                int y = __shfl_up(w, off);
                if (lane >= off) w += y;
            }
            wsum[lane] = w;
        }
        __syncthreads();
        const int carry = carry_s;
        int p = carry + (wid ? wsum[wid - 1] : 0) + (v - s);  // exclusive prefix
        int o[16];
        #pragma unroll
        for (int j = 0; j < 16; ++j) { o[j] = p; p += c[j]; }
        if (base + 16 <= n) {
            int4* qo = (int4*)(offsets + base);
            qo[0] = make_int4(o[0], o[1], o[2], o[3]);
            qo[1] = make_int4(o[4], o[5], o[6], o[7]);
            qo[2] = make_int4(o[8], o[9], o[10], o[11]);
            qo[3] = make_int4(o[12], o[13], o[14], o[15]);
        } else {
            #pragma unroll
            for (int j = 0; j < 16; ++j)
                if (base + j < n) offsets[base + j] = o[j];
        }
        if (n - 1 >= base && n - 1 < base + 16) offsets[n] = p;  // grand total
        __syncthreads();
        if (tid == 0) carry_s = carry + wsum[15];
        __syncthreads();
    }
}

// Counting-sort scatter by key = dst*NBUCK + srcbucket. Within each dst
// segment, edges end up grouped by src bucket -> all attn blocks touch the
// same ~1/8 slice of knw/v at roughly the same time (temporal locality).
__global__ __launch_bounds__(256)
void scatter_kernel(const int* __restrict__ esrc, const int* __restrict__ edst,
                    const int* __restrict__ offsets, int* __restrict__ cursor,
                    int2* __restrict__ perm, int ne, int bshift) {
    int i4 = (blockIdx.x * blockDim.x + threadIdx.x) * 4;
    if (i4 + 4 <= ne) {
        int4 d = *(const int4*)(edst + i4);
        int4 s = *(const int4*)(esrc + i4);
        int k0 = d.x * NBUCK + (s.x >> bshift);
        int p0 = offsets[k0] + atomicAdd(&cursor[k0], 1);
        perm[p0] = make_int2(s.x, i4 + 0);
        int k1 = d.y * NBUCK + (s.y >> bshift);
        int p1 = offsets[k1] + atomicAdd(&cursor[k1], 1);
        perm[p1] = make_int2(s.y, i4 + 1);
        int k2 = d.z * NBUCK + (s.z >> bshift);
        int p2 = offsets[k2] + atomicAdd(&cursor[k2], 1);
        perm[p2] = make_int2(s.z, i4 + 2);
        int k3 = d.w * NBUCK + (s.w >> bshift);
        int p3 = offsets[k3] + atomicAdd(&cursor[k3], 1);
        perm[p3] = make_int2(s.w, i4 + 3);
    } else {
        for (int j = i4; j < ne; ++j) {
            int kk = edst[j] * NBUCK + (esrc[j] >> bshift);
            int pos = offsets[kk] + atomicAdd(&cursor[kk], 1);
            perm[pos] = make_int2(esrc[j], j);
        }
    }
}

// Per-edge data held in flight (registers). kv is the pre-normalized knw row.
struct EdgeData {
    float4 ev, kv, vv;
};

__device__ __forceinline__ EdgeData load_edge(int2 p,
                                              const float* __restrict__ e,
                                              const float* __restrict__ knw,
                                              const float* __restrict__ v,
                                              int hc) {
    EdgeData d;
    // e is single-use (403 MB/pass): nontemporal so it doesn't evict knw/v.
    d.ev = nt_load4(e + (size_t)p.y * HC_DIM + hc);
    d.kv = *(const float4*)(knw + (size_t)p.x * HC_DIM + hc);
    d.vv = *(const float4*)(v + (size_t)p.x * HC_DIM + hc);
    return d;
}

// Online-softmax update. qns = rms(q)*wq*qk_scale folded per node; knw has
// wk folded, so: s = reduce8(qns . (knw + e)).
__device__ __forceinline__ void update_edge(const EdgeData& d, float4 qns,
                                            float& m, float& l, float4& acc) {
    float dd = qns.x * (d.kv.x + d.ev.x) + qns.y * (d.kv.y + d.ev.y)
             + qns.z * (d.kv.z + d.ev.z) + qns.w * (d.kv.w + d.ev.w);
    float s = reduce8(dd);
    float mnew = fmaxf(m, s);
    float sc = __expf(m - mnew);   // first edge: exp(-inf) = 0
    float al = __expf(s - mnew);
    l = l * sc + al;
    acc.x = acc.x * sc + al * (d.vv.x + d.ev.x);
    acc.y = acc.y * sc + al * (d.vv.y + d.ev.y);
    acc.z = acc.z * sc + al * (d.vv.z + d.ev.z);
    acc.w = acc.w * sc + al * (d.vv.w + d.ev.w);
    m = mnew;
}

// One block per dst node. 128 threads = 16 heads x 8 lanes; each lane owns a
// float4 of C=32. Two independent online-softmax streams (merged at the end),
// each with a 1-deep gather pipeline + perm entries carried a further
// iteration ahead. Edge list is (dst, srcbucket)-sorted for cache locality.
__global__ __launch_bounds__(128, 4)
void attn_kernel(const float* __restrict__ q, const float* __restrict__ knw,
                 const float* __restrict__ v, const float* __restrict__ e,
                 const float* __restrict__ wq,
                 const int* __restrict__ offsets, const int2* __restrict__ perm,
                 float* __restrict__ out)
{
    const int node = blockIdx.x;
    const int t = threadIdx.x;
    const int hc = t << 2;             // h*C + c4 == 4*t
    const int c4 = (t & 7) << 2;
    const int node_off = node * HC_DIM + hc;

    // fused q RMSNorm (once per node); q single-use -> nontemporal
    float4 qv = nt_load4(q + node_off);
    float qs = qv.x * qv.x + qv.y * qv.y + qv.z * qv.z + qv.w * qv.w;
    qs = reduce8(qs);
    float qinv = rsqrtf(qs * (1.0f / C_DIM) + EPSF) * QK_SCALE;
    float4 wqv = *(const float4*)(wq + c4);
    float4 qns = make_float4(qv.x * qinv * wqv.x, qv.y * qinv * wqv.y,
                             qv.z * qinv * wqv.z, qv.w * qinv * wqv.w);

    const int row0 = offsets[node * NBUCK];
    const int row1 = offsets[node * NBUCK + NBUCK];
    const int len = row1 - row0;
    const int mid = row0 + ((len + 1) >> 1);

    float mA = -INFINITY, lA = 0.0f, mB = -INFINITY, lB = 0.0f;
    float4 accA = make_float4(0.f, 0.f, 0.f, 0.f);
    float4 accB = make_float4(0.f, 0.f, 0.f, 0.f);

    int jA = row0, jB = mid;
    if (jB < row1) {                 // len >= 2: both streams non-empty
        int2 pA = perm[jA];
        int2 pB = perm[jB];
        EdgeData a = load_edge(pA, e, knw, v, hc);
        EdgeData b = load_edge(pB, e, knw, v, hc);
        ++jA; ++jB;
        bool haveNext = (jB < row1);
        int2 nA, nB;
        if (haveNext) { nA = perm[jA]; nB = perm[jB]; }
        while (haveNext) {
            EdgeData a2 = load_edge(nA, e, knw, v, hc);
            EdgeData b2 = load_edge(nB, e, knw, v, hc);
            ++jA; ++jB;
            haveNext = (jB < row1);
            if (haveNext) { nA = perm[jA]; nB = perm[jB]; }  // overlaps the updates
            update_edge(a, qns, mA, lA, accA);
            update_edge(b, qns, mB, lB, accB);
            a = a2; b = b2;
        }
        update_edge(a, qns, mA, lA, accA);
        update_edge(b, qns, mB, lB, accB);
    }
    while (jA < mid) {   // at most one extra edge (lenA = lenB or lenB+1), or len==1
        int2 p = perm[jA];
        EdgeData a = load_edge(p, e, knw, v, hc);
        update_edge(a, qns, mA, lA, accA);
        ++jA;
    }

    // merge the two streams (guard exp(-inf - -inf) = NaN for empty streams)
    float M = fmaxf(mA, mB);
    float fA = (lA > 0.0f) ? __expf(mA - M) : 0.0f;
    float fB = (lB > 0.0f) ? __expf(mB - M) : 0.0f;
    float l = lA * fA + lB * fB;
    float4 acc = make_float4(accA.x * fA + accB.x * fB,
                             accA.y * fA + accB.y * fB,
                             accA.z * fA + accB.z * fB,
                             accA.w * fA + accB.w * fB);

    float invl = (l > 0.0f) ? (1.0f / l) : 0.0f;  // empty rows -> 0 (matches ref)
    nt_store4(out + node_off, make_float4(acc.x * invl, acc.y * invl,
                                          acc.z * invl, acc.w * invl));
}

extern "C" void kernel_launch(void* const* d_in, const int* in_sizes, int n_in,
                              void* d_out, int out_size, void* d_ws, size_t ws_size,
                              hipStream_t stream) {
    const float* q  = (const float*)d_in[0];
    const float* k  = (const float*)d_in[1];
    const float* v  = (const float*)d_in[2];
    const float* e  = (const float*)d_in[3];
    const float* wq = (const float*)d_in[4];
    const float* wk = (const float*)d_in[5];
    const int* esrc = (const int*)d_in[6];
    const int* edst = (const int*)d_in[7];
    float* out = (float*)d_out;

    const int NE = in_sizes[6];
    const int HC = in_sizes[3] / NE;      // H*C
    const int N  = in_sizes[0] / HC;      // 16384

    // bucket shift: NBUCK buckets over [0, N)
    int bshift = 0;
    while ((NBUCK << bshift) < N) ++bshift;   // N=16384 -> bshift=11

    const int NB = N * NBUCK;                 // number of sort bins

    // workspace layout (16B-aligned first):
    //   perm[NE] int2 | knw[N*HC] f32 | counts[NB] | cursor[NB] | offsets[NB+1]
    char* wsp = (char*)d_ws;
    int2*  perm = (int2*)wsp;   wsp += (size_t)NE * sizeof(int2);
    float* knw  = (float*)wsp;  wsp += (size_t)N * HC_DIM * sizeof(float);
    int* counts  = (int*)wsp;
    int* cursor  = counts + NB;
    int* offsets = cursor + NB;

    const int rows = N * H_DIM;
    const int histBlocks = (NE / 4 + 255) / 256;
    const int knwBlocks  = (rows * 8 + 255) / 256;

    zero_kernel<<<(2 * NB + 255) / 256, 256, 0, stream>>>(counts, 2 * NB);
    prep_kernel<<<histBlocks + knwBlocks, 256, 0, stream>>>(
        esrc, edst, counts, k, wk, knw, NE, rows, histBlocks, bshift);
    scan_kernel<<<1, 1024, 0, stream>>>(counts, offsets, NB);
    scatter_kernel<<<(NE / 4 + 255) / 256, 256, 0, stream>>>(esrc, edst, offsets, cursor,
                                                             perm, NE, bshift);
    attn_kernel<<<N, 128, 0, stream>>>(q, knw, v, e, wq, offsets, perm, out);
}

// Round 16
// 680.315 us; speedup vs baseline: 1.1763x; 1.0383x over previous
//
#include <hip/hip_runtime.h>
#include <math.h>

// Problem constants (fixed by the reference: N=16384, H=16, C=32, NE=196608)
#define H_DIM 16
#define C_DIM 32
#define HC_DIM (H_DIM * C_DIM)   // 512
#define EPSF 1e-5f
#define QK_SCALE 0.17677669529663687f   // 1/sqrt(32)

__device__ __forceinline__ float reduce8(float x) {
    // sum across the 8 lanes that share one head (xor 1/2/4 stays in-wave)
    x += __shfl_xor(x, 1);
    x += __shfl_xor(x, 2);
    x += __shfl_xor(x, 4);
    return x;
}

// Nontemporal float4 load via clang ext_vector (float4 itself is a struct).
typedef float f4_raw __attribute__((ext_vector_type(4)));
__device__ __forceinline__ float4 nt_load4(const float* p) {
    f4_raw r = __builtin_nontemporal_load((const f4_raw*)p);
    return make_float4(r.x, r.y, r.z, r.w);
}
__device__ __forceinline__ void nt_store4(float* p, float4 v) {
    f4_raw r = {v.x, v.y, v.z, v.w};
    __builtin_nontemporal_store(r, (f4_raw*)p);
}

__global__ void zero_kernel(int* __restrict__ p, int n) {
    int i = blockIdx.x * blockDim.x + threadIdx.x;
    if (i < n) p[i] = 0;
}

// Fused pre-pass, disjoint block ranges:
//   [0, histBlocks)  : dst histogram (4 edges/thread via int4)
//   [histBlocks, ..) : knw[row] = rms(k[row])*wk  (8 lanes per (n,h) row)
__global__ __launch_bounds__(256)
void prep_kernel(const int* __restrict__ edst, int* __restrict__ counts,
                 const float* __restrict__ k, const float* __restrict__ wk,
                 float* __restrict__ knw,
                 int ne, int rows, int histBlocks) {
    int b = blockIdx.x;
    if (b < histBlocks) {
        int i4 = (b * 256 + threadIdx.x) * 4;
        if (i4 + 4 <= ne) {
            int4 d = *(const int4*)(edst + i4);
            atomicAdd(&counts[d.x], 1);
            atomicAdd(&counts[d.y], 1);
            atomicAdd(&counts[d.z], 1);
            atomicAdd(&counts[d.w], 1);
        } else {
            for (int j = i4; j < ne; ++j) atomicAdd(&counts[edst[j]], 1);
        }
        return;
    }
    int gt = (b - histBlocks) * 256 + threadIdx.x;
    int row = gt >> 3;
    if (row >= rows) return;
    const int c4 = (gt & 7) << 2;
    const size_t off = (size_t)row * C_DIM + c4;
    float4 x = *(const float4*)(k + off);
    float ss = x.x * x.x + x.y * x.y + x.z * x.z + x.w * x.w;
    ss = reduce8(ss);
    float inv = rsqrtf(ss * (1.0f / C_DIM) + EPSF);
    float4 w = *(const float4*)(wk + c4);
    *(float4*)(knw + off) = make_float4(x.x * inv * w.x, x.y * inv * w.y,
                                        x.z * inv * w.z, x.w * inv * w.w);
}

// Single-block exclusive scan over counts[n] -> offsets[n+1].
// 16 ints/thread (int4 x4): 2 barriers per 16384-chunk (n=16384 -> 1 chunk).
__global__ __launch_bounds__(1024)
void scan_kernel(const int* __restrict__ counts, int* __restrict__ offsets, int n) {
    __shared__ int wsum[16];
    __shared__ int carry_s;
    const int tid = threadIdx.x;
    const int lane = tid & 63;
    const int wid = tid >> 6;
    if (tid == 0) carry_s = 0;
    __syncthreads();
    for (int b0 = 0; b0 < n; b0 += 16384) {
        const int base = b0 + tid * 16;
        int c[16];
        if (base + 16 <= n) {
            const int4* p = (const int4*)(counts + base);
            int4 t0 = p[0], t1 = p[1], t2 = p[2], t3 = p[3];
            c[0]=t0.x; c[1]=t0.y; c[2]=t0.z; c[3]=t0.w;
            c[4]=t1.x; c[5]=t1.y; c[6]=t1.z; c[7]=t1.w;
            c[8]=t2.x; c[9]=t2.y; c[10]=t2.z; c[11]=t2.w;
            c[12]=t3.x; c[13]=t3.y; c[14]=t3.z; c[15]=t3.w;
        } else {
            #pragma unroll
            for (int j = 0; j < 16; ++j) c[j] = (base + j < n) ? counts[base + j] : 0;
        }
        int s = 0;
        #pragma unroll
        for (int j = 0; j < 16; ++j) s += c[j];
        int v = s;
        #pragma unroll
        for (int off = 1; off < 64; off <<= 1) {
            int y = __shfl_up(v, off);
            if (lane >= off) v += y;
        }
        if (lane == 63) wsum[wid] = v;
        __syncthreads();
        if (wid == 0 && lane < 16) {
            int w = wsum[lane];
            #pragma unroll
            for (int off = 1; off < 16; off <<= 1) {
                int y = __shfl_up(w, off);
                if (lane >= off) w += y;
            }
            wsum[lane] = w;
        }
        __syncthreads();
        const int carry = carry_s;
        int p = carry + (wid ? wsum[wid - 1] : 0) + (v - s);  // exclusive prefix
        int o[16];
        #pragma unroll
        for (int j = 0; j < 16; ++j) { o[j] = p; p += c[j]; }
        if (base + 16 <= n) {
            int4* qo = (int4*)(offsets + base);
            qo[0] = make_int4(o[0], o[1], o[2], o[3]);
            qo[1] = make_int4(o[4], o[5], o[6], o[7]);
            qo[2] = make_int4(o[8], o[9], o[10], o[11]);
            qo[3] = make_int4(o[12], o[13], o[14], o[15]);
        } else {
            #pragma unroll
            for (int j = 0; j < 16; ++j)
                if (base + j < n) offsets[base + j] = o[j];
        }
        if (n - 1 >= base && n - 1 < base + 16) offsets[n] = p;  // grand total
        __syncthreads();
        if (tid == 0) carry_s = carry + wsum[15];
        __syncthreads();
    }
}

// 4 edges per thread via int4 loads of esrc/edst; dst-contiguous placement.
__global__ __launch_bounds__(256)
void scatter_kernel(const int* __restrict__ esrc, const int* __restrict__ edst,
                    const int* __restrict__ offsets, int* __restrict__ cursor,
                    int2* __restrict__ perm, int ne) {
    int i4 = (blockIdx.x * blockDim.x + threadIdx.x) * 4;
    if (i4 + 4 <= ne) {
        int4 d = *(const int4*)(edst + i4);
        int4 s = *(const int4*)(esrc + i4);
        int p0 = offsets[d.x] + atomicAdd(&cursor[d.x], 1);
        perm[p0] = make_int2(s.x, i4 + 0);
        int p1 = offsets[d.y] + atomicAdd(&cursor[d.y], 1);
        perm[p1] = make_int2(s.y, i4 + 1);
        int p2 = offsets[d.z] + atomicAdd(&cursor[d.z], 1);
        perm[p2] = make_int2(s.z, i4 + 2);
        int p3 = offsets[d.w] + atomicAdd(&cursor[d.w], 1);
        perm[p3] = make_int2(s.w, i4 + 3);
    } else {
        for (int j = i4; j < ne; ++j) {
            int d = edst[j];
            int pos = offsets[d] + atomicAdd(&cursor[d], 1);
            perm[pos] = make_int2(esrc[j], j);
        }
    }
}

// Per-edge data held in flight (registers). kv is the pre-normalized knw row.
struct EdgeData {
    float4 ev, kv, vv;
};

__device__ __forceinline__ EdgeData load_edge(int2 p,
                                              const float* __restrict__ e,
                                              const float* __restrict__ knw,
                                              const float* __restrict__ v,
                                              int hc) {
    EdgeData d;
    // e is single-use (403 MB/pass): nontemporal so it doesn't evict knw/v.
    d.ev = nt_load4(e + (size_t)p.y * HC_DIM + hc);
    d.kv = *(const float4*)(knw + (size_t)p.x * HC_DIM + hc);
    d.vv = *(const float4*)(v + (size_t)p.x * HC_DIM + hc);
    return d;
}

// Online-softmax update. qns = rms(q)*wq*qk_scale folded per node; knw has
// wk folded, so: s = reduce8(qns . (knw + e)).
__device__ __forceinline__ void update_edge(const EdgeData& d, float4 qns,
                                            float& m, float& l, float4& acc) {
    float dd = qns.x * (d.kv.x + d.ev.x) + qns.y * (d.kv.y + d.ev.y)
             + qns.z * (d.kv.z + d.ev.z) + qns.w * (d.kv.w + d.ev.w);
    float s = reduce8(dd);
    float mnew = fmaxf(m, s);
    float sc = __expf(m - mnew);   // first edge: exp(-inf) = 0
    float al = __expf(s - mnew);
    l = l * sc + al;
    acc.x = acc.x * sc + al * (d.vv.x + d.ev.x);
    acc.y = acc.y * sc + al * (d.vv.y + d.ev.y);
    acc.z = acc.z * sc + al * (d.vv.z + d.ev.z);
    acc.w = acc.w * sc + al * (d.vv.w + d.ev.w);
    m = mnew;
}

// One block per dst node. 128 threads = 16 heads x 8 lanes; each lane owns a
// float4 of C=32. Two independent online-softmax streams (merged at the end),
// each with a 1-deep gather pipeline + perm entries carried a further
// iteration ahead so the perm load never fronts the gathers.
__global__ __launch_bounds__(128, 4)
void attn_kernel(const float* __restrict__ q, const float* __restrict__ knw,
                 const float* __restrict__ v, const float* __restrict__ e,
                 const float* __restrict__ wq,
                 const int* __restrict__ offsets, const int2* __restrict__ perm,
                 float* __restrict__ out)
{
    const int node = blockIdx.x;
    const int t = threadIdx.x;
    const int hc = t << 2;             // h*C + c4 == 4*t
    const int c4 = (t & 7) << 2;
    const int node_off = node * HC_DIM + hc;

    // fused q RMSNorm (once per node); q single-use -> nontemporal
    float4 qv = nt_load4(q + node_off);
    float qs = qv.x * qv.x + qv.y * qv.y + qv.z * qv.z + qv.w * qv.w;
    qs = reduce8(qs);
    float qinv = rsqrtf(qs * (1.0f / C_DIM) + EPSF) * QK_SCALE;
    float4 wqv = *(const float4*)(wq + c4);
    float4 qns = make_float4(qv.x * qinv * wqv.x, qv.y * qinv * wqv.y,
                             qv.z * qinv * wqv.z, qv.w * qinv * wqv.w);

    const int row0 = offsets[node];
    const int row1 = offsets[node + 1];
    const int len = row1 - row0;
    const int mid = row0 + ((len + 1) >> 1);

    float mA = -INFINITY, lA = 0.0f, mB = -INFINITY, lB = 0.0f;
    float4 accA = make_float4(0.f, 0.f, 0.f, 0.f);
    float4 accB = make_float4(0.f, 0.f, 0.f, 0.f);

    int jA = row0, jB = mid;
    if (jB < row1) {                 // len >= 2: both streams non-empty
        int2 pA = perm[jA];
        int2 pB = perm[jB];
        EdgeData a = load_edge(pA, e, knw, v, hc);
        EdgeData b = load_edge(pB, e, knw, v, hc);
        ++jA; ++jB;
        bool haveNext = (jB < row1);
        int2 nA, nB;
        if (haveNext) { nA = perm[jA]; nB = perm[jB]; }
        while (haveNext) {
            EdgeData a2 = load_edge(nA, e, knw, v, hc);
            EdgeData b2 = load_edge(nB, e, knw, v, hc);
            ++jA; ++jB;
            haveNext = (jB < row1);
            if (haveNext) { nA = perm[jA]; nB = perm[jB]; }  // overlaps the updates
            update_edge(a, qns, mA, lA, accA);
            update_edge(b, qns, mB, lB, accB);
            a = a2; b = b2;
        }
        update_edge(a, qns, mA, lA, accA);
        update_edge(b, qns, mB, lB, accB);
    }
    while (jA < mid) {   // at most one extra edge (lenA = lenB or lenB+1), or len==1
        int2 p = perm[jA];
        EdgeData a = load_edge(p, e, knw, v, hc);
        update_edge(a, qns, mA, lA, accA);
        ++jA;
    }

    // merge the two streams (guard exp(-inf - -inf) = NaN for empty streams)
    float M = fmaxf(mA, mB);
    float fA = (lA > 0.0f) ? __expf(mA - M) : 0.0f;
    float fB = (lB > 0.0f) ? __expf(mB - M) : 0.0f;
    float l = lA * fA + lB * fB;
    float4 acc = make_float4(accA.x * fA + accB.x * fB,
                             accA.y * fA + accB.y * fB,
                             accA.z * fA + accB.z * fB,
                             accA.w * fA + accB.w * fB);

    float invl = (l > 0.0f) ? (1.0f / l) : 0.0f;  // empty rows -> 0 (matches ref)
    nt_store4(out + node_off, make_float4(acc.x * invl, acc.y * invl,
                                          acc.z * invl, acc.w * invl));
}

extern "C" void kernel_launch(void* const* d_in, const int* in_sizes, int n_in,
                              void* d_out, int out_size, void* d_ws, size_t ws_size,
                              hipStream_t stream) {
    const float* q  = (const float*)d_in[0];
    const float* k  = (const float*)d_in[1];
    const float* v  = (const float*)d_in[2];
    const float* e  = (const float*)d_in[3];
    const float* wq = (const float*)d_in[4];
    const float* wk = (const float*)d_in[5];
    const int* esrc = (const int*)d_in[6];
    const int* edst = (const int*)d_in[7];
    float* out = (float*)d_out;

    const int NE = in_sizes[6];
    const int HC = in_sizes[3] / NE;      // H*C
    const int N  = in_sizes[0] / HC;      // 16384

    // workspace layout (16B-aligned first):
    //   perm[NE] int2 | knw[N*HC] f32 | counts[N] | cursor[N] | offsets[N+1]
    char* wsp = (char*)d_ws;
    int2*  perm = (int2*)wsp;   wsp += (size_t)NE * sizeof(int2);
    float* knw  = (float*)wsp;  wsp += (size_t)N * HC_DIM * sizeof(float);
    int* counts  = (int*)wsp;
    int* cursor  = counts + N;
    int* offsets = cursor + N;

    const int rows = N * H_DIM;
    const int histBlocks = (NE / 4 + 255) / 256;
    const int knwBlocks  = (rows * 8 + 255) / 256;

    zero_kernel<<<(2 * N + 255) / 256, 256, 0, stream>>>(counts, 2 * N);
    prep_kernel<<<histBlocks + knwBlocks, 256, 0, stream>>>(
        edst, counts, k, wk, knw, NE, rows, histBlocks);
    scan_kernel<<<1, 1024, 0, stream>>>(counts, offsets, N);
    scatter_kernel<<<(NE / 4 + 255) / 256, 256, 0, stream>>>(esrc, edst, offsets, cursor,
                                                             perm, NE);
    attn_kernel<<<N, 128, 0, stream>>>(q, knw, v, e, wq, offsets, perm, out);
}